// Round 3
// baseline (17611.179 us; speedup 1.0000x reference)
//
#include <hip/hip_runtime.h>
#include <hip/hip_bf16.h>

typedef __attribute__((ext_vector_type(8))) short shortx8;
typedef __attribute__((ext_vector_type(4))) float f32x4;
typedef __attribute__((ext_vector_type(4))) unsigned short ushortx4;

#define HDIM 512
#define DDIM 64
#define TSTEPS 512
#define NSLICE 16   // batch slices
#define NB 16       // batch per slice

__device__ __forceinline__ unsigned short f2b(float f) {
    __hip_bfloat16 h = __float2bfloat16(f);
    return *reinterpret_cast<unsigned short*>(&h);
}
__device__ __forceinline__ float b2f(unsigned short s) {
    union { unsigned int u; float f; } cvt;
    cvt.u = ((unsigned int)s) << 16;
    return cvt.f;
}
__device__ __forceinline__ float fast_tanh(float v) {
    float e = __expf(2.f * v);
    return 1.f - 2.f * __builtin_amdgcn_rcpf(e + 1.f);
}

// ---------------------------------------------------------------------------
// Prep: swizzle weights into MFMA A-fragment-major bf16 order.
// A-frag (16x16x32): lane l supplies A[row=l&15][k=(l>>4)*8+j], j=0..7.
// Chunk (mtile,kb) = 64 lanes * 16B = 1KB contiguous.
// whh0_sw: [m=32][kb=16][lane=64][8]
// w1_sw:   [m=32][kb=32][lane=64][8]   (K=1024 = [w_ih1 | w_hh1])
// wih0_sw: [m=32][kb=2 ][lane=64][8]
// ---------------------------------------------------------------------------
__global__ void prep_kernel(const float* __restrict__ w_ih0, const float* __restrict__ w_hh0,
                            const float* __restrict__ w_ih1, const float* __restrict__ w_hh1,
                            const float* __restrict__ b_ih0, const float* __restrict__ b_hh0,
                            const float* __restrict__ b_ih1, const float* __restrict__ b_hh1,
                            unsigned short* __restrict__ whh0_sw,
                            unsigned short* __restrict__ w1_sw,
                            unsigned short* __restrict__ wih0_sw,
                            float* __restrict__ bias0, float* __restrict__ bias1)
{
    int idx = blockIdx.x * blockDim.x + threadIdx.x;
    int stride = gridDim.x * blockDim.x;

    for (int i = idx; i < 32 * 16 * 64; i += stride) {
        int l = i & 63, kb = (i >> 6) & 15, m = i >> 10;
        int row = m * 16 + (l & 15);
        int k0 = kb * 32 + (l >> 4) * 8;
        unsigned short* o = whh0_sw + (size_t)i * 8;
        #pragma unroll
        for (int j = 0; j < 8; ++j) o[j] = f2b(w_hh0[row * HDIM + k0 + j]);
    }
    for (int i = idx; i < 32 * 32 * 64; i += stride) {
        int l = i & 63, kb = (i >> 6) & 31, m = i >> 11;
        int row = m * 16 + (l & 15);
        int k0 = kb * 32 + (l >> 4) * 8;
        unsigned short* o = w1_sw + (size_t)i * 8;
        #pragma unroll
        for (int j = 0; j < 8; ++j) {
            int kk = k0 + j;
            float v = (kk < HDIM) ? w_ih1[row * HDIM + kk] : w_hh1[row * HDIM + (kk - HDIM)];
            o[j] = f2b(v);
        }
    }
    for (int i = idx; i < 32 * 2 * 64; i += stride) {
        int l = i & 63, kb = (i >> 6) & 1, m = i >> 7;
        int row = m * 16 + (l & 15);
        int k0 = kb * 32 + (l >> 4) * 8;
        unsigned short* o = wih0_sw + (size_t)i * 8;
        #pragma unroll
        for (int j = 0; j < 8; ++j) o[j] = f2b(w_ih0[row * DDIM + k0 + j]);
    }
    for (int i = idx; i < HDIM; i += stride) {
        bias0[i] = b_ih0[i] + b_hh0[i];
        bias1[i] = b_ih1[i] + b_hh1[i];
    }
}

// ---------------------------------------------------------------------------
// Persistent recurrent kernel: 16 WGs x 1024 threads (16 waves), weights in
// registers (loaded once). Hidden state in LDS, B-fragment-major layout
// [kb][g][col][8]: element (kb,g,col,j) = h[col][32*kb+8*g+j].
//  - B-read: lane (g,col) b128 at ((kb*4+g)*16+col)*8  -> conflict-free floor
//  - D-write: lane (g,col), M-tile m=2w+i writes rows 16m+4g..+3 -> ushortx4
//    at ((w*4 + 2i + (g>>1))*16 + col)*8 + (g&1)*4     -> conflict-free floor
// One barrier per step (all RAW/WAR pairs barrier-separated by construction).
// ---------------------------------------------------------------------------
#define HFRAG (16 * 4 * 16 * 8)
#define XFRAG (2 * 4 * 16 * 8)

__global__ __launch_bounds__(1024, 4) void rnn_reg(
    const float* __restrict__ x,
    const unsigned short* __restrict__ whh0_sw,
    const unsigned short* __restrict__ w1_sw,
    const unsigned short* __restrict__ wih0_sw,
    const float* __restrict__ bias0,
    const float* __restrict__ bias1,
    const float* __restrict__ w_lin,
    const float* __restrict__ b_lin,
    float* __restrict__ out)
{
    __shared__ unsigned short h1f[2][HFRAG];
    __shared__ unsigned short h2f[2][HFRAG];
    __shared__ unsigned short xf[2][XFRAG];

    const int tid  = threadIdx.x;
    const int w    = tid >> 6;          // wave 0..15 (also batch row for x-stage)
    const int lane = tid & 63;
    const int g    = lane >> 4;
    const int col  = lane & 15;
    const int bslice = blockIdx.x;

    // ---- load all weight fragments into registers (once) ----
    shortx8 W0[2][16], WX[2][2], W1[2][32];
    #pragma unroll
    for (int i = 0; i < 2; ++i) {
        #pragma unroll
        for (int kb = 0; kb < 16; ++kb)
            W0[i][kb] = *reinterpret_cast<const shortx8*>(
                whh0_sw + (((size_t)((2 * w + i) * 16 + kb)) << 9) + (lane << 3));
        #pragma unroll
        for (int kb = 0; kb < 2; ++kb)
            WX[i][kb] = *reinterpret_cast<const shortx8*>(
                wih0_sw + (((size_t)((2 * w + i) * 2 + kb)) << 9) + (lane << 3));
        #pragma unroll
        for (int kb = 0; kb < 32; ++kb)
            W1[i][kb] = *reinterpret_cast<const shortx8*>(
                w1_sw + (((size_t)((2 * w + i) * 32 + kb)) << 9) + (lane << 3));
    }
    f32x4 b0f[2], b1f[2];
    #pragma unroll
    for (int i = 0; i < 2; ++i) {
        b0f[i] = *reinterpret_cast<const f32x4*>(bias0 + (2 * w + i) * 16 + g * 4);
        b1f[i] = *reinterpret_cast<const f32x4*>(bias1 + (2 * w + i) * 16 + g * 4);
    }

    // ---- init LDS state ----
    for (int i = tid; i < HFRAG; i += 1024) {
        h1f[0][i] = 0;
        h2f[0][i] = 0;
    }
    {   // x(t=0)
        int d = tid & 63;
        float xv = x[((size_t)(bslice * NB + w) * TSTEPS + 0) * DDIM + d];
        xf[0][(((d >> 5) * 4 + ((d >> 3) & 3)) * 16 + w) * 8 + (d & 7)] = f2b(xv);
    }
    __syncthreads();

    const int wr0 = ((w * 4 + 0 + (g >> 1)) * 16 + col) * 8 + (g & 1) * 4;  // i=0 D-write
    const int wr1 = ((w * 4 + 2 + (g >> 1)) * 16 + col) * 8 + (g & 1) * 4;  // i=1 D-write

#define BRD(buf, kb) (*reinterpret_cast<const shortx8*>(&(buf)[(((kb) * 4 + g) * 16 + col) * 8]))

    int cur = 0;
    for (int t = 0; t < TSTEPS; ++t) {
        const int nxt = cur ^ 1;

        // early x(t+1) global load (LDS write deferred to just before barrier)
        const int d = tid & 63;
        float xv = 0.f;
        if (t < TSTEPS - 1)
            xv = x[((size_t)(bslice * NB + w) * TSTEPS + (t + 1)) * DDIM + d];

        // ---- layer 0: h1(t) = tanh(whh0 @ h1(t-1) + wih0 @ x_t + b0) ----
        f32x4 acc0 = b0f[0], acc1 = b0f[1];
        #pragma unroll
        for (int kb = 0; kb < 16; ++kb) {
            shortx8 b = BRD(h1f[cur], kb);
            acc0 = __builtin_amdgcn_mfma_f32_16x16x32_bf16(W0[0][kb], b, acc0, 0, 0, 0);
            acc1 = __builtin_amdgcn_mfma_f32_16x16x32_bf16(W0[1][kb], b, acc1, 0, 0, 0);
        }
        #pragma unroll
        for (int kb = 0; kb < 2; ++kb) {
            shortx8 b = BRD(xf[cur], kb);
            acc0 = __builtin_amdgcn_mfma_f32_16x16x32_bf16(WX[0][kb], b, acc0, 0, 0, 0);
            acc1 = __builtin_amdgcn_mfma_f32_16x16x32_bf16(WX[1][kb], b, acc1, 0, 0, 0);
        }
        {
            ushortx4 o0, o1;
            #pragma unroll
            for (int j = 0; j < 4; ++j) {
                o0[j] = f2b(fast_tanh(acc0[j]));
                o1[j] = f2b(fast_tanh(acc1[j]));
            }
            *reinterpret_cast<ushortx4*>(&h1f[nxt][wr0]) = o0;
            *reinterpret_cast<ushortx4*>(&h1f[nxt][wr1]) = o1;
        }
        if (t < TSTEPS - 1)
            xf[nxt][(((d >> 5) * 4 + ((d >> 3) & 3)) * 16 + w) * 8 + (d & 7)] = f2b(xv);
        __syncthreads();

        // ---- layer 1: h2(t) = tanh(w_ih1 @ h1(t) + w_hh1 @ h2(t-1) + b1) ----
        f32x4 e0 = b1f[0], e1 = b1f[1];
        #pragma unroll
        for (int kb = 0; kb < 16; ++kb) {
            shortx8 b = BRD(h1f[nxt], kb);
            e0 = __builtin_amdgcn_mfma_f32_16x16x32_bf16(W1[0][kb], b, e0, 0, 0, 0);
            e1 = __builtin_amdgcn_mfma_f32_16x16x32_bf16(W1[1][kb], b, e1, 0, 0, 0);
        }
        #pragma unroll
        for (int kb = 0; kb < 16; ++kb) {
            shortx8 b = BRD(h2f[cur], kb);
            e0 = __builtin_amdgcn_mfma_f32_16x16x32_bf16(W1[0][16 + kb], b, e0, 0, 0, 0);
            e1 = __builtin_amdgcn_mfma_f32_16x16x32_bf16(W1[1][16 + kb], b, e1, 0, 0, 0);
        }
        {
            ushortx4 o0, o1;
            #pragma unroll
            for (int j = 0; j < 4; ++j) {
                o0[j] = f2b(fast_tanh(e0[j]));
                o1[j] = f2b(fast_tanh(e1[j]));
            }
            *reinterpret_cast<ushortx4*>(&h2f[nxt][wr0]) = o0;
            *reinterpret_cast<ushortx4*>(&h2f[nxt][wr1]) = o1;
        }
        cur = nxt;
        // NOTE: single barrier per step is sufficient, but the next step's
        // layer-0 writes target the buffer layer-1 just read from only after
        // this barrier at the top of the next iteration:
        __syncthreads();
    }

    // ---- final linear: out[b] = h2 . w_lin + b_lin ----
    {
        // lane l covers k = 32*(l>>2) + 8*(l&3) + j, j=0..7; batch = w
        const unsigned short* H2 = h2f[cur];
        shortx8 hv = *reinterpret_cast<const shortx8*>(
            &H2[(((lane >> 2) * 4 + (lane & 3)) * 16 + w) * 8]);
        float s = 0.f;
        #pragma unroll
        for (int j = 0; j < 8; ++j) {
            int k = 32 * (lane >> 2) + 8 * (lane & 3) + j;
            s += b2f((unsigned short)hv[j]) * w_lin[k];
        }
        #pragma unroll
        for (int off = 32; off; off >>= 1) s += __shfl_xor(s, off);
        if (lane == 0) out[bslice * NB + w] = s + b_lin[0];
    }
#undef BRD
}

extern "C" void kernel_launch(void* const* d_in, const int* in_sizes, int n_in,
                              void* d_out, int out_size, void* d_ws, size_t ws_size,
                              hipStream_t stream) {
    const float* x     = (const float*)d_in[0];
    const float* w_ih0 = (const float*)d_in[1];
    const float* w_hh0 = (const float*)d_in[2];
    const float* b_ih0 = (const float*)d_in[3];
    const float* b_hh0 = (const float*)d_in[4];
    const float* w_ih1 = (const float*)d_in[5];
    const float* w_hh1 = (const float*)d_in[6];
    const float* b_ih1 = (const float*)d_in[7];
    const float* b_hh1 = (const float*)d_in[8];
    const float* w_lin = (const float*)d_in[9];
    const float* b_lin = (const float*)d_in[10];
    float* out = (float*)d_out;

    char* ws = (char*)d_ws;
    unsigned short* whh0_sw = (unsigned short*)ws;                        // 512 KB
    unsigned short* w1_sw   = (unsigned short*)(ws + 524288);             // 1 MB
    unsigned short* wih0_sw = (unsigned short*)(ws + 524288 + 1048576);   // 64 KB
    float* bias0 = (float*)(ws + 524288 + 1048576 + 65536);               // 2 KB
    float* bias1 = (float*)(ws + 524288 + 1048576 + 65536 + 2048);        // 2 KB

    prep_kernel<<<416, 256, 0, stream>>>(w_ih0, w_hh0, w_ih1, w_hh1,
                                         b_ih0, b_hh0, b_ih1, b_hh1,
                                         whh0_sw, w1_sw, wih0_sw, bias0, bias1);
    rnn_reg<<<NSLICE, 1024, 0, stream>>>(x, whh0_sw, w1_sw, wih0_sw,
                                         bias0, bias1, w_lin, b_lin, out);
}

// Round 4
// 4691.525 us; speedup vs baseline: 3.7538x; 3.7538x over previous
//
#include <hip/hip_runtime.h>
#include <hip/hip_bf16.h>

typedef __attribute__((ext_vector_type(8))) short shortx8;
typedef __attribute__((ext_vector_type(4))) float f32x4;
typedef __attribute__((ext_vector_type(4))) unsigned short ushortx4;

#define HDIM 512
#define DDIM 64
#define TSTEPS 512
#define NG 16      // groups (batch slices of 16)
#define NB 16      // batch per group
#define SPIN_LIMIT (1u << 22)

// ws byte offsets
#define OFF_WHH0 0u
#define OFF_W1   (512u * 1024u)
#define OFF_WIH0 (OFF_W1 + 1024u * 1024u)
#define OFF_B0   (OFF_WIH0 + 64u * 1024u)
#define OFF_B1   (OFF_B0 + 2048u)
#define OFF_H1G  (OFF_B1 + 2048u)             // NG*2*16KB = 512KB
#define OFF_H2G  (OFF_H1G + 512u * 1024u)     // 512KB
#define OFF_CNT  (OFF_H2G + 512u * 1024u)     // NG*128B  (adjacent to H2G: zeroed together)

__device__ __forceinline__ unsigned short f2b(float f) {
    __hip_bfloat16 h = __float2bfloat16(f);
    return *reinterpret_cast<unsigned short*>(&h);
}
__device__ __forceinline__ float b2f(unsigned short s) {
    union { unsigned int u; float f; } cvt;
    cvt.u = ((unsigned int)s) << 16;
    return cvt.f;
}
__device__ __forceinline__ float fast_tanh(float v) {
    float e = __expf(2.f * v);
    return 1.f - 2.f * __builtin_amdgcn_rcpf(e + 1.f);
}

// ---------------------------------------------------------------------------
// Prep: swizzle weights to MFMA A-fragment-major bf16 (1KB per (mtile,kb)
// chunk), fuse biases, zero the h2 exchange buffers + counters.
// ---------------------------------------------------------------------------
__global__ void prep_kernel(const float* __restrict__ w_ih0, const float* __restrict__ w_hh0,
                            const float* __restrict__ w_ih1, const float* __restrict__ w_hh1,
                            const float* __restrict__ b_ih0, const float* __restrict__ b_hh0,
                            const float* __restrict__ b_ih1, const float* __restrict__ b_hh1,
                            unsigned short* __restrict__ whh0_sw,
                            unsigned short* __restrict__ w1_sw,
                            unsigned short* __restrict__ wih0_sw,
                            float* __restrict__ bias0, float* __restrict__ bias1,
                            unsigned int* __restrict__ zero32, int nzero)
{
    int idx = blockIdx.x * blockDim.x + threadIdx.x;
    int stride = gridDim.x * blockDim.x;

    for (int i = idx; i < 32 * 16 * 64; i += stride) {
        int l = i & 63, kb = (i >> 6) & 15, mt = i >> 10;
        int row = mt * 16 + (l & 15);
        int k0 = kb * 32 + (l >> 4) * 8;
        unsigned short* o = whh0_sw + (size_t)i * 8;
        #pragma unroll
        for (int j = 0; j < 8; ++j) o[j] = f2b(w_hh0[row * HDIM + k0 + j]);
    }
    for (int i = idx; i < 32 * 32 * 64; i += stride) {
        int l = i & 63, kb = (i >> 6) & 31, mt = i >> 11;
        int row = mt * 16 + (l & 15);
        int k0 = kb * 32 + (l >> 4) * 8;
        unsigned short* o = w1_sw + (size_t)i * 8;
        #pragma unroll
        for (int j = 0; j < 8; ++j) {
            int kk = k0 + j;
            float v = (kk < HDIM) ? w_ih1[row * HDIM + kk] : w_hh1[row * HDIM + (kk - HDIM)];
            o[j] = f2b(v);
        }
    }
    for (int i = idx; i < 32 * 2 * 64; i += stride) {
        int l = i & 63, kb = (i >> 6) & 1, mt = i >> 7;
        int row = mt * 16 + (l & 15);
        int k0 = kb * 32 + (l >> 4) * 8;
        unsigned short* o = wih0_sw + (size_t)i * 8;
        #pragma unroll
        for (int j = 0; j < 8; ++j) o[j] = f2b(w_ih0[row * DDIM + k0 + j]);
    }
    for (int i = idx; i < HDIM; i += stride) {
        bias0[i] = b_ih0[i] + b_hh0[i];
        bias1[i] = b_ih1[i] + b_hh1[i];
    }
    for (int i = idx; i < nzero; i += stride) zero32[i] = 0u;
}

// ---------------------------------------------------------------------------
// 16 groups x 4 CUs. CU m owns rows [128m,128m+128) of both layers; wave w
// owns M-tiles mt0=8m+2w, mt1=mt0+1. All weights register-resident (400 VGPR).
// Hidden state exchanged per step through L2 with release/acquire counters.
// Frag-major h layout: elem (row r, col) at ((r>>3)*16+col)*8 + (r&7).
//   B-read (lane gq,col, kb): offset kb*512 + gq*128 + col*8  (shortx8)
//   D-write (lane gq,col, tile mt): mt*256 + (gq>>1)*128 + col*8 + (gq&1)*4
// Hazard audit (X writes vs Y reads): h1G[q]: A1(t) w -> B2(t) r (cntA spin);
//   WAR A1(t) vs B2(t-2) r: X@A1(t) passed B1(t-1) spin <= Y@B2(t-2). h2G[q]:
//   A3(t) w -> B2(t+1) r (cntB spin); WAR A3(t) vs B2(t-1) r: X@A3(t) passed
//   B1(t) cntA>=4(t+1) <= Y finished A1(t) > Y's B2(t-1). All safe.
// ---------------------------------------------------------------------------
__global__ __launch_bounds__(256, 1) void rnn_mc(
    const float* __restrict__ x,
    const unsigned short* __restrict__ whh0_sw,
    const unsigned short* __restrict__ w1_sw,
    const unsigned short* __restrict__ wih0_sw,
    const float* __restrict__ bias0,
    const float* __restrict__ bias1,
    const float* __restrict__ w_lin,
    const float* __restrict__ b_lin,
    unsigned short* __restrict__ h1G,
    unsigned short* __restrict__ h2G,
    unsigned int* __restrict__ cnt,
    float* __restrict__ out)
{
    // 100KB LDS: forces 1 WG/CU (co-residency of all 64 WGs guaranteed).
    __shared__ unsigned short h1L[2][16384];
    __shared__ unsigned short h2L[16384];
    __shared__ unsigned short xL[2][1024];

    const int tid  = threadIdx.x;
    const int w    = tid >> 6;
    const int lane = tid & 63;
    const int gq   = lane >> 4;
    const int col  = lane & 15;
    const int b    = blockIdx.x;
    const int g    = (b & 7) | ((b >> 5) << 3);   // group: 4 members share one XCD
    const int m    = (b >> 3) & 3;                // member 0..3

    const int mt0 = m * 8 + 2 * w, mt1 = mt0 + 1;
    const int lbase = gq * 128 + col * 8;
    const int dbase = (gq >> 1) * 128 + col * 8 + (gq & 1) * 4;

    unsigned int* cntA = cnt + g * 32;
    unsigned int* cntB = cnt + g * 32 + 16;

    // ---- weights -> registers, once; pinned against remat ----
    shortx8 W0a[18], W0b[18], W1a[32], W1b[32];
    #pragma unroll
    for (int kb = 0; kb < 16; ++kb) {
        W0a[kb] = *(const shortx8*)(whh0_sw + (((size_t)(mt0 * 16 + kb)) << 9) + lane * 8);
        W0b[kb] = *(const shortx8*)(whh0_sw + (((size_t)(mt1 * 16 + kb)) << 9) + lane * 8);
    }
    #pragma unroll
    for (int kx = 0; kx < 2; ++kx) {
        W0a[16 + kx] = *(const shortx8*)(wih0_sw + (((size_t)(mt0 * 2 + kx)) << 9) + lane * 8);
        W0b[16 + kx] = *(const shortx8*)(wih0_sw + (((size_t)(mt1 * 2 + kx)) << 9) + lane * 8);
    }
    #pragma unroll
    for (int kb = 0; kb < 32; ++kb) {
        W1a[kb] = *(const shortx8*)(w1_sw + (((size_t)(mt0 * 32 + kb)) << 9) + lane * 8);
        W1b[kb] = *(const shortx8*)(w1_sw + (((size_t)(mt1 * 32 + kb)) << 9) + lane * 8);
    }
    #pragma unroll
    for (int i = 0; i < 18; ++i) { asm volatile("" : "+v"(W0a[i]), "+v"(W0b[i])); }
    #pragma unroll
    for (int i = 0; i < 32; ++i) { asm volatile("" : "+v"(W1a[i]), "+v"(W1b[i])); }

    f32x4 b0a = *(const f32x4*)(bias0 + mt0 * 16 + gq * 4);
    f32x4 b0b = *(const f32x4*)(bias0 + mt1 * 16 + gq * 4);
    f32x4 b1a = *(const f32x4*)(bias1 + mt0 * 16 + gq * 4);
    f32x4 b1b = *(const f32x4*)(bias1 + mt1 * 16 + gq * 4);

    // ---- init: h1(-1)=0 local; stage x(0) ----
    {
        shortx8 zz = {0, 0, 0, 0, 0, 0, 0, 0};
        for (int i = tid * 8; i < 8192; i += 256 * 8) *(shortx8*)&h1L[0][i] = zz;
        int bb = tid >> 4, d4 = (tid & 15) * 4;
        f32x4 xv = *(const f32x4*)&x[((size_t)(g * NB + bb) * TSTEPS + 0) * DDIM + d4];
        ushortx4 o;
        o[0] = f2b(xv[0]); o[1] = f2b(xv[1]); o[2] = f2b(xv[2]); o[3] = f2b(xv[3]);
        *(ushortx4*)&xL[0][((d4 >> 3) * 16 + bb) * 8 + (d4 & 7)] = o;
    }
    __syncthreads();

    bool bail = false;
    for (int t = 0; t < TSTEPS; ++t) {
        const int p = t & 1, q = p ^ 1;
        unsigned short* h1Gq = h1G + (g * 2 + q) * 8192;
        unsigned short* h2Gq = h2G + (g * 2 + q) * 8192;
        const unsigned short* h2Gp = h2G + (g * 2 + p) * 8192;

        // ---- A1: layer0 on own rows:  h1(t) = tanh(whh0@h1(t-1) + wih0@x(t) + b0)
        f32x4 acc0 = b0a, acc1 = b0b;
        #pragma unroll
        for (int kb = 0; kb < 16; ++kb) {
            shortx8 bf = *(const shortx8*)&h1L[p][kb * 512 + lbase];
            acc0 = __builtin_amdgcn_mfma_f32_16x16x32_bf16(W0a[kb], bf, acc0, 0, 0, 0);
            acc1 = __builtin_amdgcn_mfma_f32_16x16x32_bf16(W0b[kb], bf, acc1, 0, 0, 0);
        }
        #pragma unroll
        for (int kx = 0; kx < 2; ++kx) {
            shortx8 bf = *(const shortx8*)&xL[p][kx * 512 + lbase];
            acc0 = __builtin_amdgcn_mfma_f32_16x16x32_bf16(W0a[16 + kx], bf, acc0, 0, 0, 0);
            acc1 = __builtin_amdgcn_mfma_f32_16x16x32_bf16(W0b[16 + kx], bf, acc1, 0, 0, 0);
        }
        {
            ushortx4 o0, o1;
            #pragma unroll
            for (int j = 0; j < 4; ++j) { o0[j] = f2b(fast_tanh(acc0[j])); o1[j] = f2b(fast_tanh(acc1[j])); }
            *(ushortx4*)(h1Gq + mt0 * 256 + dbase) = o0;   // publish own h1 chunk
            *(ushortx4*)(h1Gq + mt1 * 256 + dbase) = o1;
        }

        // ---- B1: release h1; wait for peers' h2(t-1) and h1(t) ----
        __syncthreads();                                    // drains vmcnt before barrier
        if (tid == 0) {
            __threadfence();
            __hip_atomic_fetch_add(cntA, 1u, __ATOMIC_RELEASE, __HIP_MEMORY_SCOPE_AGENT);
            unsigned tgtB = 4u * (unsigned)t, tgtA = 4u * (unsigned)(t + 1), it = 0;
            if (!bail) {
                while (__hip_atomic_load(cntB, __ATOMIC_ACQUIRE, __HIP_MEMORY_SCOPE_AGENT) < tgtB) {
                    __builtin_amdgcn_s_sleep(1);
                    if (++it > SPIN_LIMIT) { bail = true; break; }
                }
                while (!bail && __hip_atomic_load(cntA, __ATOMIC_ACQUIRE, __HIP_MEMORY_SCOPE_AGENT) < tgtA) {
                    __builtin_amdgcn_s_sleep(1);
                    if (++it > SPIN_LIMIT) { bail = true; break; }
                }
            }
            __threadfence();                                // acquire: invalidates L1
        }
        __syncthreads();

        // ---- B2: stage h2(t-1) and h1(t) full vectors, x(t+1) ----
        {
            int o = tid * 8;
            #pragma unroll
            for (int j = 0; j < 4; ++j) {
                int e = o + j * 2048;
                *(shortx8*)&h2L[e]    = *(const shortx8*)(h2Gp + e);
                *(shortx8*)&h1L[q][e] = *(const shortx8*)(h1Gq + e);
            }
        }
        if (t + 1 < TSTEPS) {
            int bb = tid >> 4, d4 = (tid & 15) * 4;
            f32x4 xv = *(const f32x4*)&x[((size_t)(g * NB + bb) * TSTEPS + (t + 1)) * DDIM + d4];
            ushortx4 o;
            o[0] = f2b(xv[0]); o[1] = f2b(xv[1]); o[2] = f2b(xv[2]); o[3] = f2b(xv[3]);
            *(ushortx4*)&xL[q][((d4 >> 3) * 16 + bb) * 8 + (d4 & 7)] = o;
        }
        __syncthreads();

        // ---- A3: layer1 on own rows: h2(t) = tanh(w_ih1@h1(t) + w_hh1@h2(t-1) + b1)
        f32x4 e0 = b1a, e1 = b1b;
        #pragma unroll
        for (int kb = 0; kb < 16; ++kb) {
            shortx8 bf = *(const shortx8*)&h1L[q][kb * 512 + lbase];
            e0 = __builtin_amdgcn_mfma_f32_16x16x32_bf16(W1a[kb], bf, e0, 0, 0, 0);
            e1 = __builtin_amdgcn_mfma_f32_16x16x32_bf16(W1b[kb], bf, e1, 0, 0, 0);
        }
        #pragma unroll
        for (int kb = 0; kb < 16; ++kb) {
            shortx8 bf = *(const shortx8*)&h2L[kb * 512 + lbase];
            e0 = __builtin_amdgcn_mfma_f32_16x16x32_bf16(W1a[16 + kb], bf, e0, 0, 0, 0);
            e1 = __builtin_amdgcn_mfma_f32_16x16x32_bf16(W1b[16 + kb], bf, e1, 0, 0, 0);
        }
        {
            ushortx4 o0, o1;
            #pragma unroll
            for (int j = 0; j < 4; ++j) { o0[j] = f2b(fast_tanh(e0[j])); o1[j] = f2b(fast_tanh(e1[j])); }
            *(ushortx4*)(h2Gq + mt0 * 256 + dbase) = o0;   // publish own h2 chunk
            *(ushortx4*)(h2Gq + mt1 * 256 + dbase) = o1;
        }

        // ---- B4: release h2 ----
        __syncthreads();
        if (tid == 0) {
            __threadfence();
            __hip_atomic_fetch_add(cntB, 1u, __ATOMIC_RELEASE, __HIP_MEMORY_SCOPE_AGENT);
        }
    }

    // ---- final linear (member 0 of each group) ----
    if (m == 0) {
        if (tid == 0) {
            unsigned it = 0;
            while (!bail && __hip_atomic_load(cntB, __ATOMIC_ACQUIRE, __HIP_MEMORY_SCOPE_AGENT) < 4u * TSTEPS) {
                __builtin_amdgcn_s_sleep(1);
                if (++it > SPIN_LIMIT) break;
            }
            __threadfence();
        }
        __syncthreads();
        const unsigned short* h2f = h2G + (g * 2 + 0) * 8192;   // q at t=511 is 0
        #pragma unroll
        for (int r = 0; r < 4; ++r) {
            int bb = w * 4 + r;
            shortx8 hv = *(const shortx8*)(h2f + lane * 128 + bb * 8);
            f32x4 wl0 = *(const f32x4*)&w_lin[lane * 8];
            f32x4 wl1 = *(const f32x4*)&w_lin[lane * 8 + 4];
            float s = b2f((unsigned short)hv[0]) * wl0[0] + b2f((unsigned short)hv[1]) * wl0[1]
                    + b2f((unsigned short)hv[2]) * wl0[2] + b2f((unsigned short)hv[3]) * wl0[3]
                    + b2f((unsigned short)hv[4]) * wl1[0] + b2f((unsigned short)hv[5]) * wl1[1]
                    + b2f((unsigned short)hv[6]) * wl1[2] + b2f((unsigned short)hv[7]) * wl1[3];
            #pragma unroll
            for (int off = 32; off; off >>= 1) s += __shfl_xor(s, off);
            if (lane == 0) out[g * NB + bb] = s + b_lin[0];
        }
    }
}

extern "C" void kernel_launch(void* const* d_in, const int* in_sizes, int n_in,
                              void* d_out, int out_size, void* d_ws, size_t ws_size,
                              hipStream_t stream) {
    const float* x     = (const float*)d_in[0];
    const float* w_ih0 = (const float*)d_in[1];
    const float* w_hh0 = (const float*)d_in[2];
    const float* b_ih0 = (const float*)d_in[3];
    const float* b_hh0 = (const float*)d_in[4];
    const float* w_ih1 = (const float*)d_in[5];
    const float* w_hh1 = (const float*)d_in[6];
    const float* b_ih1 = (const float*)d_in[7];
    const float* b_hh1 = (const float*)d_in[8];
    const float* w_lin = (const float*)d_in[9];
    const float* b_lin = (const float*)d_in[10];
    float* out = (float*)d_out;

    char* ws = (char*)d_ws;
    unsigned short* whh0_sw = (unsigned short*)(ws + OFF_WHH0);
    unsigned short* w1_sw   = (unsigned short*)(ws + OFF_W1);
    unsigned short* wih0_sw = (unsigned short*)(ws + OFF_WIH0);
    float* bias0            = (float*)(ws + OFF_B0);
    float* bias1            = (float*)(ws + OFF_B1);
    unsigned short* h1G     = (unsigned short*)(ws + OFF_H1G);
    unsigned short* h2G     = (unsigned short*)(ws + OFF_H2G);
    unsigned int*   cnt     = (unsigned int*)(ws + OFF_CNT);

    // zero h2G + counters (adjacent regions)
    unsigned int* zero32 = (unsigned int*)(ws + OFF_H2G);
    int nzero = (512 * 1024 + NG * 128) / 4;

    prep_kernel<<<416, 256, 0, stream>>>(w_ih0, w_hh0, w_ih1, w_hh1,
                                         b_ih0, b_hh0, b_ih1, b_hh1,
                                         whh0_sw, w1_sw, wih0_sw, bias0, bias1,
                                         zero32, nzero);
    rnn_mc<<<64, 256, 0, stream>>>(x, whh0_sw, w1_sw, wih0_sw, bias0, bias1,
                                   w_lin, b_lin, h1G, h2G, cnt, out);
}

// Round 5
// 2465.748 us; speedup vs baseline: 7.1423x; 1.9027x over previous
//
#include <hip/hip_runtime.h>
#include <hip/hip_bf16.h>

typedef __attribute__((ext_vector_type(8))) short shortx8;
typedef __attribute__((ext_vector_type(4))) float f32x4;
typedef __attribute__((ext_vector_type(4))) unsigned short ushortx4;

#define HDIM 512
#define DDIM 64
#define TSTEPS 512
#define NG 16      // groups (batch slices of 16)
#define NB 16      // batch per group
#define SPIN_LIMIT (1u << 20)

// ws byte offsets
#define OFF_WHH0 0u
#define OFF_W1   (512u * 1024u)
#define OFF_WIH0 (OFF_W1 + 1024u * 1024u)
#define OFF_B0   (OFF_WIH0 + 64u * 1024u)
#define OFF_B1   (OFF_B0 + 2048u)
#define OFF_H1G  (OFF_B1 + 2048u)             // NG*2*16KB = 512KB
#define OFF_H2G  (OFF_H1G + 512u * 1024u)     // 512KB
#define OFF_CNT  (OFF_H2G + 512u * 1024u)     // NG*128B

__device__ __forceinline__ unsigned short f2b(float f) {
    __hip_bfloat16 h = __float2bfloat16(f);
    return *reinterpret_cast<unsigned short*>(&h);
}
__device__ __forceinline__ float b2f(unsigned short s) {
    union { unsigned int u; float f; } cvt;
    cvt.u = ((unsigned int)s) << 16;
    return cvt.f;
}
__device__ __forceinline__ float fast_tanh(float v) {
    float e = __expf(2.f * v);
    return 1.f - 2.f * __builtin_amdgcn_rcpf(e + 1.f);
}

// ---- MALL-homed (Infinity-Cache-coherent) memory ops: sc0 sc1 = bypass L1+L2.
// XCD-independent coherence without any cache-invalidate/writeback fences.
__device__ __forceinline__ void mall_store8(unsigned short* p, ushortx4 v) {
    asm volatile("global_store_dwordx2 %0, %1, off sc0 sc1" :: "v"(p), "v"(v) : "memory");
}
__device__ __forceinline__ shortx8 mall_load16(const unsigned short* p) {
    shortx8 r;
    asm volatile("global_load_dwordx4 %0, %1, off sc0 sc1" : "=v"(r) : "v"(p) : "memory");
    return r;   // NOT waited — caller must vm_drain() before use
}
__device__ __forceinline__ void vm_drain() {
    asm volatile("s_waitcnt vmcnt(0)" ::: "memory");
    __builtin_amdgcn_sched_barrier(0);
}
__device__ __forceinline__ void mall_atomic_inc(unsigned int* p) {
    unsigned int one = 1u;
    asm volatile("global_atomic_add %0, %1, off sc1" :: "v"(p), "v"(one) : "memory");
}
__device__ __forceinline__ unsigned int mall_read_u32(const unsigned int* p) {
    unsigned int r;
    asm volatile("global_load_dword %0, %1, off sc0 sc1\n\ts_waitcnt vmcnt(0)"
                 : "=v"(r) : "v"(p) : "memory");
    return r;
}
__device__ __forceinline__ bool poll_ge(unsigned int* p, unsigned int tgt) {
    unsigned int it = 0;
    while (mall_read_u32(p) < tgt) {
        __builtin_amdgcn_s_sleep(1);
        if (++it > SPIN_LIMIT) return false;
    }
    return true;
}

// ---------------------------------------------------------------------------
// Prep: swizzle weights to MFMA A-fragment-major bf16; fuse biases; zero the
// sync counters WITH sc0/sc1 stores (they live at MALL — a plain zero would
// sit dirty in one XCD's L2 and the MALL-homed atomics would never see it).
// ---------------------------------------------------------------------------
__global__ void prep_kernel(const float* __restrict__ w_ih0, const float* __restrict__ w_hh0,
                            const float* __restrict__ w_ih1, const float* __restrict__ w_hh1,
                            const float* __restrict__ b_ih0, const float* __restrict__ b_hh0,
                            const float* __restrict__ b_ih1, const float* __restrict__ b_hh1,
                            unsigned short* __restrict__ whh0_sw,
                            unsigned short* __restrict__ w1_sw,
                            unsigned short* __restrict__ wih0_sw,
                            float* __restrict__ bias0, float* __restrict__ bias1,
                            unsigned int* __restrict__ cnt)
{
    int idx = blockIdx.x * blockDim.x + threadIdx.x;
    int stride = gridDim.x * blockDim.x;

    for (int i = idx; i < 32 * 16 * 64; i += stride) {
        int l = i & 63, kb = (i >> 6) & 15, mt = i >> 10;
        int row = mt * 16 + (l & 15);
        int k0 = kb * 32 + (l >> 4) * 8;
        unsigned short* o = whh0_sw + (size_t)i * 8;
        #pragma unroll
        for (int j = 0; j < 8; ++j) o[j] = f2b(w_hh0[row * HDIM + k0 + j]);
    }
    for (int i = idx; i < 32 * 32 * 64; i += stride) {
        int l = i & 63, kb = (i >> 6) & 31, mt = i >> 11;
        int row = mt * 16 + (l & 15);
        int k0 = kb * 32 + (l >> 4) * 8;
        unsigned short* o = w1_sw + (size_t)i * 8;
        #pragma unroll
        for (int j = 0; j < 8; ++j) {
            int kk = k0 + j;
            float v = (kk < HDIM) ? w_ih1[row * HDIM + kk] : w_hh1[row * HDIM + (kk - HDIM)];
            o[j] = f2b(v);
        }
    }
    for (int i = idx; i < 32 * 2 * 64; i += stride) {
        int l = i & 63, kb = (i >> 6) & 1, mt = i >> 7;
        int row = mt * 16 + (l & 15);
        int k0 = kb * 32 + (l >> 4) * 8;
        unsigned short* o = wih0_sw + (size_t)i * 8;
        #pragma unroll
        for (int j = 0; j < 8; ++j) o[j] = f2b(w_ih0[row * DDIM + k0 + j]);
    }
    for (int i = idx; i < HDIM; i += stride) {
        bias0[i] = b_ih0[i] + b_hh0[i];
        bias1[i] = b_ih1[i] + b_hh1[i];
    }
    if (idx < NG * 32) {
        unsigned int z = 0;
        unsigned int* p = cnt + idx;
        asm volatile("global_store_dword %0, %1, off sc0 sc1" :: "v"(p), "v"(z) : "memory");
    }
}

// ---------------------------------------------------------------------------
// 16 groups x 4 CUs. CU m owns rows [128m,128m+128); wave w owns M-tiles
// mt0=8m+2w, mt1=mt0+1; all weights register-resident. ONE exchange round per
// step: iteration t computes h1(t+1) (A1) and h2(t) (A3), publishes both via
// MALL; h1-stage loads issue before A3 and drain after it (latency hidden).
// Frag-major h layout: elem (row r, col) at ((r>>3)*16+col)*8 + (r&7).
//   B-read (lane gq,col, kb): kb*512 + gq*128 + col*8        (shortx8)
//   D-write (tile mt): mt*256 + (gq>>1)*128 + col*8 + (gq&1)*4
// Hazard audit: buffer parity s&1, one-round separation; publish(s+2) occurs
// only after own stage(s+1) which required all peers' publish(s+1) which
// followed their stage(s) — so no writer overtakes any reader. Counters are
// monotonic; all data+counters MALL-homed (single serialization point).
// ---------------------------------------------------------------------------
__global__ __launch_bounds__(256, 1) void rnn_mall(
    const float* __restrict__ x,
    const unsigned short* __restrict__ whh0_sw,
    const unsigned short* __restrict__ w1_sw,
    const unsigned short* __restrict__ wih0_sw,
    const float* __restrict__ bias0,
    const float* __restrict__ bias1,
    const float* __restrict__ w_lin,
    const float* __restrict__ b_lin,
    unsigned short* __restrict__ h1G,
    unsigned short* __restrict__ h2G,
    unsigned int* __restrict__ cnt,
    float* __restrict__ out)
{
    __shared__ unsigned short h1L[2][8192];
    __shared__ unsigned short h2L[2][8192];
    __shared__ unsigned short xL[2][1024];

    const int tid  = threadIdx.x;
    const int w    = tid >> 6;
    const int lane = tid & 63;
    const int gq   = lane >> 4;
    const int col  = lane & 15;
    const int b    = blockIdx.x;
    const int g    = (b & 7) | ((b >> 5) << 3);
    const int m    = (b >> 3) & 3;

    const int mt0 = m * 8 + 2 * w, mt1 = mt0 + 1;
    const int lbase = gq * 128 + col * 8;
    const int dbase = (gq >> 1) * 128 + col * 8 + (gq & 1) * 4;

    unsigned int* cntA = cnt + g * 32;
    unsigned int* cntB = cnt + g * 32 + 16;

    // ---- weights -> registers, once; pinned ----
    shortx8 W0a[18], W0b[18], W1a[32], W1b[32];
    #pragma unroll
    for (int kb = 0; kb < 16; ++kb) {
        W0a[kb] = *(const shortx8*)(whh0_sw + (((size_t)(mt0 * 16 + kb)) << 9) + lane * 8);
        W0b[kb] = *(const shortx8*)(whh0_sw + (((size_t)(mt1 * 16 + kb)) << 9) + lane * 8);
    }
    #pragma unroll
    for (int kx = 0; kx < 2; ++kx) {
        W0a[16 + kx] = *(const shortx8*)(wih0_sw + (((size_t)(mt0 * 2 + kx)) << 9) + lane * 8);
        W0b[16 + kx] = *(const shortx8*)(wih0_sw + (((size_t)(mt1 * 2 + kx)) << 9) + lane * 8);
    }
    #pragma unroll
    for (int kb = 0; kb < 32; ++kb) {
        W1a[kb] = *(const shortx8*)(w1_sw + (((size_t)(mt0 * 32 + kb)) << 9) + lane * 8);
        W1b[kb] = *(const shortx8*)(w1_sw + (((size_t)(mt1 * 32 + kb)) << 9) + lane * 8);
    }
    #pragma unroll
    for (int i = 0; i < 18; ++i) { asm volatile("" : "+v"(W0a[i]), "+v"(W0b[i])); }
    #pragma unroll
    for (int i = 0; i < 32; ++i) { asm volatile("" : "+v"(W1a[i]), "+v"(W1b[i])); }

    f32x4 b0a = *(const f32x4*)(bias0 + mt0 * 16 + gq * 4);
    f32x4 b0b = *(const f32x4*)(bias0 + mt1 * 16 + gq * 4);
    f32x4 b1a = *(const f32x4*)(bias1 + mt0 * 16 + gq * 4);
    f32x4 b1b = *(const f32x4*)(bias1 + mt1 * 16 + gq * 4);

    const int bb = tid >> 4, d4 = (tid & 15) * 4;
    const int xo = ((d4 >> 3) * 16 + bb) * 8 + (d4 & 7);
    const float* xrow = x + (size_t)(g * NB + bb) * TSTEPS * DDIM + d4;
    bool bail = false;

    // ---- prologue: x(0)->xL[0], x(1)->xL[1]; h2(-1)=0; h1(0) compute+exchange
    {
        f32x4 x0 = *(const f32x4*)(xrow);
        f32x4 x1 = *(const f32x4*)(xrow + DDIM);
        ushortx4 o0, o1;
        #pragma unroll
        for (int j = 0; j < 4; ++j) { o0[j] = f2b(x0[j]); o1[j] = f2b(x1[j]); }
        *(ushortx4*)&xL[0][xo] = o0;
        *(ushortx4*)&xL[1][xo] = o1;
        shortx8 zz = {0, 0, 0, 0, 0, 0, 0, 0};
        for (int i = tid * 8; i < 8192; i += 2048) *(shortx8*)&h2L[1][i] = zz;
    }
    __syncthreads();
    {
        unsigned short* h1G0 = h1G + (size_t)(g * 2 + 0) * 8192;
        f32x4 acc0 = b0a, acc1 = b0b;
        #pragma unroll
        for (int kx = 0; kx < 2; ++kx) {
            shortx8 bf = *(const shortx8*)&xL[0][kx * 512 + lbase];
            acc0 = __builtin_amdgcn_mfma_f32_16x16x32_bf16(W0a[16 + kx], bf, acc0, 0, 0, 0);
            acc1 = __builtin_amdgcn_mfma_f32_16x16x32_bf16(W0b[16 + kx], bf, acc1, 0, 0, 0);
        }
        ushortx4 o0, o1;
        #pragma unroll
        for (int j = 0; j < 4; ++j) { o0[j] = f2b(fast_tanh(acc0[j])); o1[j] = f2b(fast_tanh(acc1[j])); }
        mall_store8(h1G0 + mt0 * 256 + dbase, o0);
        mall_store8(h1G0 + mt1 * 256 + dbase, o1);
        vm_drain();
        __syncthreads();
        if (tid == 0) { mall_atomic_inc(cntA); if (!poll_ge(cntA, 4u)) bail = true; }
        __syncthreads();
        int o = tid * 8;
        shortx8 v0 = mall_load16(h1G0 + o);
        shortx8 v1 = mall_load16(h1G0 + o + 2048);
        shortx8 v2 = mall_load16(h1G0 + o + 4096);
        shortx8 v3 = mall_load16(h1G0 + o + 6144);
        vm_drain();
        *(shortx8*)&h1L[0][o]        = v0;
        *(shortx8*)&h1L[0][o + 2048] = v1;
        *(shortx8*)&h1L[0][o + 4096] = v2;
        *(shortx8*)&h1L[0][o + 6144] = v3;
    }
    __syncthreads();

    // ---- main loop: iteration t computes h1(t+1) and h2(t) ----
    for (int t = 0; t < TSTEPS - 1; ++t) {
        const int pc = t & 1, pn = pc ^ 1;
        unsigned short* h1Gn = h1G + (size_t)(g * 2 + pn) * 8192;
        unsigned short* h2Gc = h2G + (size_t)(g * 2 + pc) * 8192;

        // x(t+2) prefetch (plain cached load; used next iteration)
        const bool havex = (t + 2 < TSTEPS);
        f32x4 xv;
        if (havex) xv = *(const f32x4*)(xrow + (size_t)(t + 2) * DDIM);

        // A1: h1(t+1) = tanh(whh0 @ h1(t) + wih0 @ x(t+1) + b0)
        f32x4 acc0 = b0a, acc1 = b0b;
        #pragma unroll
        for (int kb = 0; kb < 16; ++kb) {
            shortx8 bf = *(const shortx8*)&h1L[pc][kb * 512 + lbase];
            acc0 = __builtin_amdgcn_mfma_f32_16x16x32_bf16(W0a[kb], bf, acc0, 0, 0, 0);
            acc1 = __builtin_amdgcn_mfma_f32_16x16x32_bf16(W0b[kb], bf, acc1, 0, 0, 0);
        }
        #pragma unroll
        for (int kx = 0; kx < 2; ++kx) {
            shortx8 bf = *(const shortx8*)&xL[pn][kx * 512 + lbase];
            acc0 = __builtin_amdgcn_mfma_f32_16x16x32_bf16(W0a[16 + kx], bf, acc0, 0, 0, 0);
            acc1 = __builtin_amdgcn_mfma_f32_16x16x32_bf16(W0b[16 + kx], bf, acc1, 0, 0, 0);
        }
        {
            ushortx4 o0, o1;
            #pragma unroll
            for (int j = 0; j < 4; ++j) { o0[j] = f2b(fast_tanh(acc0[j])); o1[j] = f2b(fast_tanh(acc1[j])); }
            mall_store8(h1Gn + mt0 * 256 + dbase, o0);
            mall_store8(h1Gn + mt1 * 256 + dbase, o1);
        }
        if (havex) {
            ushortx4 ox;
            #pragma unroll
            for (int j = 0; j < 4; ++j) ox[j] = f2b(xv[j]);
            *(ushortx4*)&xL[pc][xo] = ox;
        }
        vm_drain();
        __syncthreads();
        if (tid == 0) { mall_atomic_inc(cntA); if (!poll_ge(cntA, 4u * (t + 2))) bail = true; }
        __syncthreads();

        // issue h1(t+1) stage loads (drained after A3 — hidden under MFMA)
        const int o = tid * 8;
        shortx8 va0 = mall_load16(h1Gn + o);
        shortx8 va1 = mall_load16(h1Gn + o + 2048);
        shortx8 va2 = mall_load16(h1Gn + o + 4096);
        shortx8 va3 = mall_load16(h1Gn + o + 6144);

        // A3: h2(t) = tanh(w_ih1 @ h1(t) + w_hh1 @ h2(t-1) + b1)
        f32x4 e0 = b1a, e1 = b1b;
        #pragma unroll
        for (int kb = 0; kb < 16; ++kb) {
            shortx8 bf = *(const shortx8*)&h1L[pc][kb * 512 + lbase];
            e0 = __builtin_amdgcn_mfma_f32_16x16x32_bf16(W1a[kb], bf, e0, 0, 0, 0);
            e1 = __builtin_amdgcn_mfma_f32_16x16x32_bf16(W1b[kb], bf, e1, 0, 0, 0);
        }
        #pragma unroll
        for (int kb = 0; kb < 16; ++kb) {
            shortx8 bf = *(const shortx8*)&h2L[pn][kb * 512 + lbase];
            e0 = __builtin_amdgcn_mfma_f32_16x16x32_bf16(W1a[16 + kb], bf, e0, 0, 0, 0);
            e1 = __builtin_amdgcn_mfma_f32_16x16x32_bf16(W1b[16 + kb], bf, e1, 0, 0, 0);
        }
        {
            ushortx4 o0, o1;
            #pragma unroll
            for (int j = 0; j < 4; ++j) { o0[j] = f2b(fast_tanh(e0[j])); o1[j] = f2b(fast_tanh(e1[j])); }
            mall_store8(h2Gc + mt0 * 256 + dbase, o0);
            mall_store8(h2Gc + mt1 * 256 + dbase, o1);
        }
        vm_drain();                         // drains va* loads AND h2 publish
        *(shortx8*)&h1L[pn][o]        = va0;
        *(shortx8*)&h1L[pn][o + 2048] = va1;
        *(shortx8*)&h1L[pn][o + 4096] = va2;
        *(shortx8*)&h1L[pn][o + 6144] = va3;
        __syncthreads();
        if (tid == 0) { mall_atomic_inc(cntB); if (!poll_ge(cntB, 4u * (t + 1))) bail = true; }
        __syncthreads();

        // stage h2(t) -> h2L[pc]  (barrier deferred to next iteration's A1 sync)
        shortx8 vb0 = mall_load16(h2Gc + o);
        shortx8 vb1 = mall_load16(h2Gc + o + 2048);
        shortx8 vb2 = mall_load16(h2Gc + o + 4096);
        shortx8 vb3 = mall_load16(h2Gc + o + 6144);
        vm_drain();
        *(shortx8*)&h2L[pc][o]        = vb0;
        *(shortx8*)&h2L[pc][o + 2048] = vb1;
        *(shortx8*)&h2L[pc][o + 4096] = vb2;
        *(shortx8*)&h2L[pc][o + 6144] = vb3;
    }

    // ---- epilogue: h2(511) = tanh(w_ih1 @ h1(511) + w_hh1 @ h2(510) + b1) ----
    __syncthreads();
    {
        unsigned short* h2Gc = h2G + (size_t)(g * 2 + 1) * 8192;
        f32x4 e0 = b1a, e1 = b1b;
        #pragma unroll
        for (int kb = 0; kb < 16; ++kb) {
            shortx8 bf = *(const shortx8*)&h1L[1][kb * 512 + lbase];
            e0 = __builtin_amdgcn_mfma_f32_16x16x32_bf16(W1a[kb], bf, e0, 0, 0, 0);
            e1 = __builtin_amdgcn_mfma_f32_16x16x32_bf16(W1b[kb], bf, e1, 0, 0, 0);
        }
        #pragma unroll
        for (int kb = 0; kb < 16; ++kb) {
            shortx8 bf = *(const shortx8*)&h2L[0][kb * 512 + lbase];
            e0 = __builtin_amdgcn_mfma_f32_16x16x32_bf16(W1a[16 + kb], bf, e0, 0, 0, 0);
            e1 = __builtin_amdgcn_mfma_f32_16x16x32_bf16(W1b[16 + kb], bf, e1, 0, 0, 0);
        }
        ushortx4 o0, o1;
        #pragma unroll
        for (int j = 0; j < 4; ++j) { o0[j] = f2b(fast_tanh(e0[j])); o1[j] = f2b(fast_tanh(e1[j])); }
        mall_store8(h2Gc + mt0 * 256 + dbase, o0);
        mall_store8(h2Gc + mt1 * 256 + dbase, o1);
        vm_drain();
        __syncthreads();
        if (tid == 0) mall_atomic_inc(cntB);

        // final linear on member 0
        if (m == 0) {
            if (tid == 0) poll_ge(cntB, 4u * TSTEPS);
            __syncthreads();
            #pragma unroll
            for (int r = 0; r < 4; ++r) {
                int bx = w * 4 + r;
                shortx8 hv = mall_load16(h2Gc + lane * 128 + bx * 8);
                vm_drain();
                float s = 0.f;
                #pragma unroll
                for (int j = 0; j < 8; ++j)
                    s += b2f((unsigned short)hv[j]) * w_lin[lane * 8 + j];
                #pragma unroll
                for (int off = 32; off; off >>= 1) s += __shfl_xor(s, off);
                if (lane == 0) out[g * NB + bx] = s + b_lin[0];
            }
        }
    }
    if (bail && tid == 0 && b == 0) out[0] = out[0];  // keep bail live (no-op)
}

extern "C" void kernel_launch(void* const* d_in, const int* in_sizes, int n_in,
                              void* d_out, int out_size, void* d_ws, size_t ws_size,
                              hipStream_t stream) {
    const float* x     = (const float*)d_in[0];
    const float* w_ih0 = (const float*)d_in[1];
    const float* w_hh0 = (const float*)d_in[2];
    const float* b_ih0 = (const float*)d_in[3];
    const float* b_hh0 = (const float*)d_in[4];
    const float* w_ih1 = (const float*)d_in[5];
    const float* w_hh1 = (const float*)d_in[6];
    const float* b_ih1 = (const float*)d_in[7];
    const float* b_hh1 = (const float*)d_in[8];
    const float* w_lin = (const float*)d_in[9];
    const float* b_lin = (const float*)d_in[10];
    float* out = (float*)d_out;

    char* ws = (char*)d_ws;
    unsigned short* whh0_sw = (unsigned short*)(ws + OFF_WHH0);
    unsigned short* w1_sw   = (unsigned short*)(ws + OFF_W1);
    unsigned short* wih0_sw = (unsigned short*)(ws + OFF_WIH0);
    float* bias0            = (float*)(ws + OFF_B0);
    float* bias1            = (float*)(ws + OFF_B1);
    unsigned short* h1G     = (unsigned short*)(ws + OFF_H1G);
    unsigned short* h2G     = (unsigned short*)(ws + OFF_H2G);
    unsigned int*   cnt     = (unsigned int*)(ws + OFF_CNT);

    prep_kernel<<<416, 256, 0, stream>>>(w_ih0, w_hh0, w_ih1, w_hh1,
                                         b_ih0, b_hh0, b_ih1, b_hh1,
                                         whh0_sw, w1_sw, wih0_sw, bias0, bias1, cnt);
    rnn_mall<<<64, 256, 0, stream>>>(x, whh0_sw, w1_sw, wih0_sw, bias0, bias1,
                                     w_lin, b_lin, h1G, h2G, cnt, out);
}

// Round 6
// 1801.246 us; speedup vs baseline: 9.7772x; 1.3689x over previous
//
#include <hip/hip_runtime.h>
#include <hip/hip_bf16.h>

typedef __attribute__((ext_vector_type(8))) short shortx8;
typedef __attribute__((ext_vector_type(4))) float f32x4;
typedef __attribute__((ext_vector_type(4))) unsigned short ushortx4;
typedef __attribute__((ext_vector_type(4))) unsigned int u32x4;

#define HDIM 512
#define DDIM 64
#define TSTEPS 512
#define NG 16      // groups (batch slices of 16)
#define NB 16      // batch per group
#define SPIN_LIMIT (1u << 16)

// ws byte offsets
#define OFF_WHH0 0u
#define OFF_W1   (512u * 1024u)
#define OFF_WIH0 (OFF_W1 + 1024u * 1024u)
#define OFF_B0   (OFF_WIH0 + 64u * 1024u)
#define OFF_B1   (OFF_B0 + 2048u)
#define OFF_H1G  (OFF_B1 + 2048u)             // NG*2*16KB = 512KB
#define OFF_H2G  (OFF_H1G + 512u * 1024u)     // 512KB
#define OFF_CNT  (OFF_H2G + 512u * 1024u)     // NG*128B

__device__ __forceinline__ unsigned short f2b(float f) {
    __hip_bfloat16 h = __float2bfloat16(f);
    return *reinterpret_cast<unsigned short*>(&h);
}
__device__ __forceinline__ float b2f(unsigned short s) {
    union { unsigned int u; float f; } cvt;
    cvt.u = ((unsigned int)s) << 16;
    return cvt.f;
}
__device__ __forceinline__ float fast_tanh(float v) {
    float e = __expf(2.f * v);
    return 1.f - 2.f * __builtin_amdgcn_rcpf(e + 1.f);
}

// ---- MALL-homed (Infinity-Cache-coherent) ops: sc0 sc1 = bypass L1+L2 ----
__device__ __forceinline__ void mall_store8(unsigned short* p, ushortx4 v) {
    asm volatile("global_store_dwordx2 %0, %1, off sc0 sc1" :: "v"(p), "v"(v) : "memory");
}
__device__ __forceinline__ shortx8 mall_load16(const unsigned short* p) {
    shortx8 r;
    asm volatile("global_load_dwordx4 %0, %1, off sc0 sc1" : "=v"(r) : "v"(p) : "memory");
    return r;   // NOT waited — caller must vm_drain() before use
}
__device__ __forceinline__ void vm_drain() {
    asm volatile("s_waitcnt vmcnt(0)" ::: "memory");
    __builtin_amdgcn_sched_barrier(0);
}
__device__ __forceinline__ void flag_store(unsigned int* p, unsigned int v) {
    asm volatile("global_store_dword %0, %1, off sc0 sc1" :: "v"(p), "v"(v) : "memory");
}
// Wait until the 3 PEER flags reach tgt (own flag excluded: own data already
// drained; skipping it avoids a self store->load MALL round-trip).
__device__ __forceinline__ bool poll_peers(const unsigned int* fp, int m,
                                           unsigned int tgt, bool bail) {
    if (bail) return false;
    unsigned it = 0;
    for (;;) {
        u32x4 f;
        asm volatile("global_load_dwordx4 %0, %1, off sc0 sc1\n\ts_waitcnt vmcnt(0)"
                     : "=v"(f) : "v"(fp) : "memory");
        bool ok = true;
        if (m != 0 && f[0] < tgt) ok = false;
        if (m != 1 && f[1] < tgt) ok = false;
        if (m != 2 && f[2] < tgt) ok = false;
        if (m != 3 && f[3] < tgt) ok = false;
        if (ok) return true;
        if (++it > SPIN_LIMIT) return false;
    }
}

// ---------------------------------------------------------------------------
// Prep: swizzle weights to MFMA A-fragment-major bf16; fuse biases; zero sync
// flags with sc0/sc1 stores (flags are MALL-homed; a plain zero could sit
// dirty in one XCD's L2 where MALL-scope readers never see it).
// ---------------------------------------------------------------------------
__global__ void prep_kernel(const float* __restrict__ w_ih0, const float* __restrict__ w_hh0,
                            const float* __restrict__ w_ih1, const float* __restrict__ w_hh1,
                            const float* __restrict__ b_ih0, const float* __restrict__ b_hh0,
                            const float* __restrict__ b_ih1, const float* __restrict__ b_hh1,
                            unsigned short* __restrict__ whh0_sw,
                            unsigned short* __restrict__ w1_sw,
                            unsigned short* __restrict__ wih0_sw,
                            float* __restrict__ bias0, float* __restrict__ bias1,
                            unsigned int* __restrict__ cnt)
{
    int idx = blockIdx.x * blockDim.x + threadIdx.x;
    int stride = gridDim.x * blockDim.x;

    for (int i = idx; i < 32 * 16 * 64; i += stride) {
        int l = i & 63, kb = (i >> 6) & 15, mt = i >> 10;
        int row = mt * 16 + (l & 15);
        int k0 = kb * 32 + (l >> 4) * 8;
        unsigned short* o = whh0_sw + (size_t)i * 8;
        #pragma unroll
        for (int j = 0; j < 8; ++j) o[j] = f2b(w_hh0[row * HDIM + k0 + j]);
    }
    for (int i = idx; i < 32 * 32 * 64; i += stride) {
        int l = i & 63, kb = (i >> 6) & 31, mt = i >> 11;
        int row = mt * 16 + (l & 15);
        int k0 = kb * 32 + (l >> 4) * 8;
        unsigned short* o = w1_sw + (size_t)i * 8;
        #pragma unroll
        for (int j = 0; j < 8; ++j) {
            int kk = k0 + j;
            float v = (kk < HDIM) ? w_ih1[row * HDIM + kk] : w_hh1[row * HDIM + (kk - HDIM)];
            o[j] = f2b(v);
        }
    }
    for (int i = idx; i < 32 * 2 * 64; i += stride) {
        int l = i & 63, kb = (i >> 6) & 1, mt = i >> 7;
        int row = mt * 16 + (l & 15);
        int k0 = kb * 32 + (l >> 4) * 8;
        unsigned short* o = wih0_sw + (size_t)i * 8;
        #pragma unroll
        for (int j = 0; j < 8; ++j) o[j] = f2b(w_ih0[row * DDIM + k0 + j]);
    }
    for (int i = idx; i < HDIM; i += stride) {
        bias0[i] = b_ih0[i] + b_hh0[i];
        bias1[i] = b_ih1[i] + b_hh1[i];
    }
    if (idx < NG * 32) {
        unsigned int z = 0;
        unsigned int* p = cnt + idx;
        asm volatile("global_store_dword %0, %1, off sc0 sc1" :: "v"(p), "v"(z) : "memory");
    }
}

// ---------------------------------------------------------------------------
// 16 groups x 4 CUs; CU m owns rows [128m,128m+128); weights register-resident.
// ONE sync round per step: iteration t computes h1(t+1) (A1) AND h2(t) (A3)
// back-to-back from local LDS (A3 needs nothing from this step's exchange),
// publishes both, one flag round (store own, poll 3 peers), stages both.
// Flag protocol: prologue=1, iteration t stores t+2 (2..512), epilogue=513.
// Hazard: flag=v implies that member's stage(v-3) reads drained (they drain
// inside iteration v-3, before compute(v-2) which precedes flag=v) => any
// writer at iteration v-1 re-using the v-3 parity buffer is WAR-safe. RAW:
// publishes vm_drained before barrier before flag store.
// ---------------------------------------------------------------------------
__global__ __launch_bounds__(256, 1) void rnn_1sync(
    const float* __restrict__ x,
    const unsigned short* __restrict__ whh0_sw,
    const unsigned short* __restrict__ w1_sw,
    const unsigned short* __restrict__ wih0_sw,
    const float* __restrict__ bias0,
    const float* __restrict__ bias1,
    const float* __restrict__ w_lin,
    const float* __restrict__ b_lin,
    unsigned short* __restrict__ h1G,
    unsigned short* __restrict__ h2G,
    unsigned int* __restrict__ cnt,
    float* __restrict__ out)
{
    __shared__ unsigned short h1L[2][8192];
    __shared__ unsigned short h2L[2][8192];
    __shared__ unsigned short xL[2][1024];

    const int tid  = threadIdx.x;
    const int w    = tid >> 6;
    const int lane = tid & 63;
    const int gq   = lane >> 4;
    const int col  = lane & 15;
    const int b    = blockIdx.x;
    const int g    = (b & 7) | ((b >> 5) << 3);   // 4 members share one XCD (perf only)
    const int m    = (b >> 3) & 3;

    const int mt0 = m * 8 + 2 * w, mt1 = mt0 + 1;
    const int lbase = gq * 128 + col * 8;
    const int dbase = (gq >> 1) * 128 + col * 8 + (gq & 1) * 4;

    unsigned int* flags = cnt + g * 32;           // 4 dwords in one 16B line

    // ---- weights -> registers, once; pinned ----
    shortx8 W0a[18], W0b[18], W1a[32], W1b[32];
    #pragma unroll
    for (int kb = 0; kb < 16; ++kb) {
        W0a[kb] = *(const shortx8*)(whh0_sw + (((size_t)(mt0 * 16 + kb)) << 9) + lane * 8);
        W0b[kb] = *(const shortx8*)(whh0_sw + (((size_t)(mt1 * 16 + kb)) << 9) + lane * 8);
    }
    #pragma unroll
    for (int kx = 0; kx < 2; ++kx) {
        W0a[16 + kx] = *(const shortx8*)(wih0_sw + (((size_t)(mt0 * 2 + kx)) << 9) + lane * 8);
        W0b[16 + kx] = *(const shortx8*)(wih0_sw + (((size_t)(mt1 * 2 + kx)) << 9) + lane * 8);
    }
    #pragma unroll
    for (int kb = 0; kb < 32; ++kb) {
        W1a[kb] = *(const shortx8*)(w1_sw + (((size_t)(mt0 * 32 + kb)) << 9) + lane * 8);
        W1b[kb] = *(const shortx8*)(w1_sw + (((size_t)(mt1 * 32 + kb)) << 9) + lane * 8);
    }
    #pragma unroll
    for (int i = 0; i < 18; ++i) { asm volatile("" : "+v"(W0a[i]), "+v"(W0b[i])); }
    #pragma unroll
    for (int i = 0; i < 32; ++i) { asm volatile("" : "+v"(W1a[i]), "+v"(W1b[i])); }

    f32x4 b0a = *(const f32x4*)(bias0 + mt0 * 16 + gq * 4);
    f32x4 b0b = *(const f32x4*)(bias0 + mt1 * 16 + gq * 4);
    f32x4 b1a = *(const f32x4*)(bias1 + mt0 * 16 + gq * 4);
    f32x4 b1b = *(const f32x4*)(bias1 + mt1 * 16 + gq * 4);

    const int bb = tid >> 4, d4 = (tid & 15) * 4;
    const int xo = ((d4 >> 3) * 16 + bb) * 8 + (d4 & 7);
    const float* xrow = x + (size_t)(g * NB + bb) * TSTEPS * DDIM + d4;
    bool bail = false;

    // ---- prologue: xL[0]=x(0), xL[1]=x(1); h2(-1)=0; h1(0) compute+exchange
    {
        f32x4 x0 = *(const f32x4*)(xrow);
        f32x4 x1 = *(const f32x4*)(xrow + DDIM);
        ushortx4 o0, o1;
        #pragma unroll
        for (int j = 0; j < 4; ++j) { o0[j] = f2b(x0[j]); o1[j] = f2b(x1[j]); }
        *(ushortx4*)&xL[0][xo] = o0;
        *(ushortx4*)&xL[1][xo] = o1;
        shortx8 zz = {0, 0, 0, 0, 0, 0, 0, 0};
        for (int i = tid * 8; i < 8192; i += 2048) *(shortx8*)&h2L[1][i] = zz;
    }
    __syncthreads();
    {
        unsigned short* h1G0 = h1G + (size_t)(g * 2 + 0) * 8192;
        f32x4 acc0 = b0a, acc1 = b0b;
        #pragma unroll
        for (int kx = 0; kx < 2; ++kx) {
            shortx8 bf = *(const shortx8*)&xL[0][kx * 512 + lbase];
            acc0 = __builtin_amdgcn_mfma_f32_16x16x32_bf16(W0a[16 + kx], bf, acc0, 0, 0, 0);
            acc1 = __builtin_amdgcn_mfma_f32_16x16x32_bf16(W0b[16 + kx], bf, acc1, 0, 0, 0);
        }
        ushortx4 o0, o1;
        #pragma unroll
        for (int j = 0; j < 4; ++j) { o0[j] = f2b(fast_tanh(acc0[j])); o1[j] = f2b(fast_tanh(acc1[j])); }
        mall_store8(h1G0 + mt0 * 256 + dbase, o0);
        mall_store8(h1G0 + mt1 * 256 + dbase, o1);
        vm_drain();
        __syncthreads();
        if (tid == 0) flag_store(flags + m, 1u);
        if (!poll_peers(flags, m, 1u, bail)) bail = true;
        int o = tid * 8;
        shortx8 v0 = mall_load16(h1G0 + o);
        shortx8 v1 = mall_load16(h1G0 + o + 2048);
        shortx8 v2 = mall_load16(h1G0 + o + 4096);
        shortx8 v3 = mall_load16(h1G0 + o + 6144);
        vm_drain();
        *(shortx8*)&h1L[0][o]        = v0;
        *(shortx8*)&h1L[0][o + 2048] = v1;
        *(shortx8*)&h1L[0][o + 4096] = v2;
        *(shortx8*)&h1L[0][o + 6144] = v3;
    }
    __syncthreads();

    // ---- main loop: iteration t computes h1(t+1) AND h2(t); one sync round ----
    for (int t = 0; t < TSTEPS - 1; ++t) {
        const int pc = t & 1, pn = pc ^ 1;
        unsigned short* h1Gn = h1G + (size_t)(g * 2 + pn) * 8192;  // h1(t+1)
        unsigned short* h2Gc = h2G + (size_t)(g * 2 + pc) * 8192;  // h2(t)

        const bool havex = (t + 2 < TSTEPS);
        f32x4 xv;
        if (havex) xv = *(const f32x4*)(xrow + (size_t)(t + 2) * DDIM);

        // fused A1 + A3-part1: one h1L read feeds 4 MFMAs
        f32x4 acc0 = b0a, acc1 = b0b, e0 = b1a, e1 = b1b;
        #pragma unroll
        for (int kb = 0; kb < 16; ++kb) {
            shortx8 bf = *(const shortx8*)&h1L[pc][kb * 512 + lbase];
            acc0 = __builtin_amdgcn_mfma_f32_16x16x32_bf16(W0a[kb], bf, acc0, 0, 0, 0);
            acc1 = __builtin_amdgcn_mfma_f32_16x16x32_bf16(W0b[kb], bf, acc1, 0, 0, 0);
            e0   = __builtin_amdgcn_mfma_f32_16x16x32_bf16(W1a[kb], bf, e0, 0, 0, 0);
            e1   = __builtin_amdgcn_mfma_f32_16x16x32_bf16(W1b[kb], bf, e1, 0, 0, 0);
        }
        #pragma unroll
        for (int kx = 0; kx < 2; ++kx) {
            shortx8 bf = *(const shortx8*)&xL[pn][kx * 512 + lbase];
            acc0 = __builtin_amdgcn_mfma_f32_16x16x32_bf16(W0a[16 + kx], bf, acc0, 0, 0, 0);
            acc1 = __builtin_amdgcn_mfma_f32_16x16x32_bf16(W0b[16 + kx], bf, acc1, 0, 0, 0);
        }
        #pragma unroll
        for (int kb = 0; kb < 16; ++kb) {
            shortx8 bf = *(const shortx8*)&h2L[pn][kb * 512 + lbase];
            e0 = __builtin_amdgcn_mfma_f32_16x16x32_bf16(W1a[16 + kb], bf, e0, 0, 0, 0);
            e1 = __builtin_amdgcn_mfma_f32_16x16x32_bf16(W1b[16 + kb], bf, e1, 0, 0, 0);
        }

        // publish h1(t+1) and h2(t)
        {
            ushortx4 o0, o1, p0, p1;
            #pragma unroll
            for (int j = 0; j < 4; ++j) {
                o0[j] = f2b(fast_tanh(acc0[j])); o1[j] = f2b(fast_tanh(acc1[j]));
                p0[j] = f2b(fast_tanh(e0[j]));   p1[j] = f2b(fast_tanh(e1[j]));
            }
            mall_store8(h1Gn + mt0 * 256 + dbase, o0);
            mall_store8(h1Gn + mt1 * 256 + dbase, o1);
            mall_store8(h2Gc + mt0 * 256 + dbase, p0);
            mall_store8(h2Gc + mt1 * 256 + dbase, p1);
        }
        if (havex) {
            ushortx4 ox;
            #pragma unroll
            for (int j = 0; j < 4; ++j) ox[j] = f2b(xv[j]);
            *(ushortx4*)&xL[pc][xo] = ox;
        }
        vm_drain();
        __syncthreads();

        // one flag round: store own, poll 3 peers (all threads poll)
        const unsigned int tgt = (unsigned int)(t + 2);
        if (tid == 0) flag_store(flags + m, tgt);
        if (!poll_peers(flags, m, tgt, bail)) bail = true;

        // stage h1(t+1) -> h1L[pn], h2(t) -> h2L[pc]  (8 loads in flight)
        const int o = tid * 8;
        shortx8 va0 = mall_load16(h1Gn + o);
        shortx8 va1 = mall_load16(h1Gn + o + 2048);
        shortx8 va2 = mall_load16(h1Gn + o + 4096);
        shortx8 va3 = mall_load16(h1Gn + o + 6144);
        shortx8 vb0 = mall_load16(h2Gc + o);
        shortx8 vb1 = mall_load16(h2Gc + o + 2048);
        shortx8 vb2 = mall_load16(h2Gc + o + 4096);
        shortx8 vb3 = mall_load16(h2Gc + o + 6144);
        vm_drain();
        *(shortx8*)&h1L[pn][o]        = va0;
        *(shortx8*)&h1L[pn][o + 2048] = va1;
        *(shortx8*)&h1L[pn][o + 4096] = va2;
        *(shortx8*)&h1L[pn][o + 6144] = va3;
        *(shortx8*)&h2L[pc][o]        = vb0;
        *(shortx8*)&h2L[pc][o + 2048] = vb1;
        *(shortx8*)&h2L[pc][o + 4096] = vb2;
        *(shortx8*)&h2L[pc][o + 6144] = vb3;
        __syncthreads();
    }

    // ---- epilogue: h2(511) = tanh(w_ih1 @ h1(511) + w_hh1 @ h2(510) + b1) ----
    {
        unsigned short* h2Gc = h2G + (size_t)(g * 2 + 1) * 8192;
        f32x4 e0 = b1a, e1 = b1b;
        #pragma unroll
        for (int kb = 0; kb < 16; ++kb) {
            shortx8 bf = *(const shortx8*)&h1L[1][kb * 512 + lbase];
            e0 = __builtin_amdgcn_mfma_f32_16x16x32_bf16(W1a[kb], bf, e0, 0, 0, 0);
            e1 = __builtin_amdgcn_mfma_f32_16x16x32_bf16(W1b[kb], bf, e1, 0, 0, 0);
        }
        #pragma unroll
        for (int kb = 0; kb < 16; ++kb) {
            shortx8 bf = *(const shortx8*)&h2L[0][kb * 512 + lbase];
            e0 = __builtin_amdgcn_mfma_f32_16x16x32_bf16(W1a[16 + kb], bf, e0, 0, 0, 0);
            e1 = __builtin_amdgcn_mfma_f32_16x16x32_bf16(W1b[16 + kb], bf, e1, 0, 0, 0);
        }
        ushortx4 o0, o1;
        #pragma unroll
        for (int j = 0; j < 4; ++j) { o0[j] = f2b(fast_tanh(e0[j])); o1[j] = f2b(fast_tanh(e1[j])); }
        mall_store8(h2Gc + mt0 * 256 + dbase, o0);
        mall_store8(h2Gc + mt1 * 256 + dbase, o1);
        vm_drain();
        __syncthreads();
        if (tid == 0) flag_store(flags + m, (unsigned int)(TSTEPS + 1));

        // final linear on member 0
        if (m == 0) {
            if (!poll_peers(flags, m, (unsigned int)(TSTEPS + 1), bail)) bail = true;
            #pragma unroll
            for (int r = 0; r < 4; ++r) {
                int bx = w * 4 + r;
                shortx8 hv = mall_load16(h2Gc + lane * 128 + bx * 8);
                vm_drain();
                float s = 0.f;
                #pragma unroll
                for (int j = 0; j < 8; ++j)
                    s += b2f((unsigned short)hv[j]) * w_lin[lane * 8 + j];
                #pragma unroll
                for (int off = 32; off; off >>= 1) s += __shfl_xor(s, off);
                if (lane == 0) out[g * NB + bx] = s + b_lin[0];
            }
        }
    }
    if (bail && tid == 0 && b == 0) out[0] = out[0];  // keep bail live (no-op)
}

extern "C" void kernel_launch(void* const* d_in, const int* in_sizes, int n_in,
                              void* d_out, int out_size, void* d_ws, size_t ws_size,
                              hipStream_t stream) {
    const float* x     = (const float*)d_in[0];
    const float* w_ih0 = (const float*)d_in[1];
    const float* w_hh0 = (const float*)d_in[2];
    const float* b_ih0 = (const float*)d_in[3];
    const float* b_hh0 = (const float*)d_in[4];
    const float* w_ih1 = (const float*)d_in[5];
    const float* w_hh1 = (const float*)d_in[6];
    const float* b_ih1 = (const float*)d_in[7];
    const float* b_hh1 = (const float*)d_in[8];
    const float* w_lin = (const float*)d_in[9];
    const float* b_lin = (const float*)d_in[10];
    float* out = (float*)d_out;

    char* ws = (char*)d_ws;
    unsigned short* whh0_sw = (unsigned short*)(ws + OFF_WHH0);
    unsigned short* w1_sw   = (unsigned short*)(ws + OFF_W1);
    unsigned short* wih0_sw = (unsigned short*)(ws + OFF_WIH0);
    float* bias0            = (float*)(ws + OFF_B0);
    float* bias1            = (float*)(ws + OFF_B1);
    unsigned short* h1G     = (unsigned short*)(ws + OFF_H1G);
    unsigned short* h2G     = (unsigned short*)(ws + OFF_H2G);
    unsigned int*   cnt     = (unsigned int*)(ws + OFF_CNT);

    prep_kernel<<<416, 256, 0, stream>>>(w_ih0, w_hh0, w_ih1, w_hh1,
                                         b_ih0, b_hh0, b_ih1, b_hh1,
                                         whh0_sw, w1_sw, wih0_sw, bias0, bias1, cnt);
    rnn_1sync<<<64, 256, 0, stream>>>(x, whh0_sw, w1_sw, wih0_sw, bias0, bias1,
                                      w_lin, b_lin, h1G, h2G, cnt, out);
}